// Round 3
// baseline (298.530 us; speedup 1.0000x reference)
//
#include <hip/hip_runtime.h>
#include <math.h>

#define NB 64            // blocks for hist/scatter passes

// ---------------- kernel 1: per-block LDS histogram + merge -----------------
// rb[b*S+s] = running offset of block b's elements of sample s within counts[s]
__global__ __launch_bounds__(1024) void k_hist2(const int* __restrict__ idx,
                                                int* __restrict__ counts,
                                                int* __restrict__ rb,
                                                int n, int S) {
    __shared__ int lh[8192];
    int t = threadIdx.x, b = blockIdx.x;
    for (int s = t; s < S; s += 1024) lh[s] = 0;
    __syncthreads();
    int chunk = (n + NB - 1) / NB;
    int lo = b * chunk;
    int hi = min(n, lo + chunk);
    for (int i = lo + t; i < hi; i += 1024) atomicAdd(&lh[idx[i]], 1);
    __syncthreads();
    for (int s = t; s < S; s += 1024) {
        int h = lh[s];
        rb[b * S + s] = (h > 0) ? atomicAdd(&counts[s], h) : 0;
    }
}

// ---------------- kernel 2: exclusive prefix scan (single block, S<=8192) ---
__global__ __launch_bounds__(1024) void k_scan(const int* __restrict__ counts,
                                               int* __restrict__ base, int S) {
    __shared__ int sh[1024];
    int t = threadIdx.x;
    int loc[8];
    int sum = 0;
#pragma unroll
    for (int j = 0; j < 8; ++j) {
        int g = t * 8 + j;
        loc[j] = sum;                       // exclusive within thread
        sum += (g < S) ? counts[g] : 0;
    }
    sh[t] = sum;
    __syncthreads();
    int total = sum;
    for (int off = 1; off < 1024; off <<= 1) {
        int v = (t >= off) ? sh[t - off] : 0;
        __syncthreads();
        sh[t] += v;
        __syncthreads();
    }
    int excl = sh[t] - total;               // exclusive across threads
#pragma unroll
    for (int j = 0; j < 8; ++j) {
        int g = t * 8 + j;
        if (g < S) base[g] = excl + loc[j];
    }
}

// ---------------- kernel 3: scatter via LDS cursors -------------------------
__global__ __launch_bounds__(1024) void k_scatter2(const int* __restrict__ idx,
                                                   const int* __restrict__ base,
                                                   const int* __restrict__ rb,
                                                   int* __restrict__ order,
                                                   int n, int S) {
    __shared__ int cur[8192];
    int t = threadIdx.x, b = blockIdx.x;
    for (int s = t; s < S; s += 1024) cur[s] = base[s] + rb[b * S + s];
    __syncthreads();
    int chunk = (n + NB - 1) / NB;
    int lo = b * chunk;
    int hi = min(n, lo + chunk);
    for (int i = lo + t; i < hi; i += 1024) {
        int s = idx[i];
        int pos = atomicAdd(&cur[s], 1);
        order[pos] = i;
    }
}

// ---------------- kernel 4: per-sample online softmax-pool ------------------
// One wave per sample. 4 groups of 16 lanes; group g handles element e+g.
// Lane owns dims 8*(lane&15)..+7. Software pipeline: order index fetched two
// iterations ahead, rows one iteration ahead -> no serial order->row chain.
__global__ __launch_bounds__(256, 4) void k_pool(
        const float* __restrict__ emb, const float* __restrict__ w_att,
        const int* __restrict__ base, const int* __restrict__ counts,
        const int* __restrict__ order, float* __restrict__ pooled, int S) {
    int wave = (blockIdx.x << 2) | (threadIdx.x >> 6);
    int lane = threadIdx.x & 63;
    if (wave >= S) return;
    int g   = lane >> 4;                    // element group 0..3
    int l16 = lane & 15;                    // lane within group
    int b   = base[wave];
    int cnt = counts[wave];
    const float* wrow = w_att + 8 * l16;
    float4 wa0 = *reinterpret_cast<const float4*>(wrow);
    float4 wa1 = *reinterpret_cast<const float4*>(wrow + 4);
    float4 a0 = make_float4(0.f, 0.f, 0.f, 0.f);
    float4 a1 = make_float4(0.f, 0.f, 0.f, 0.f);
    float Z = 0.f;
    if (cnt > 0) {
        const int* ob = order + b;
        int last = cnt - 1;
        int e = g;
        int i_cur = ob[min(e, last)];
        int i_nxt = ob[min(e + 4, last)];
        const float* r = emb + (size_t)i_cur * 128 + 8 * l16;
        float4 v0 = *reinterpret_cast<const float4*>(r);
        float4 v1 = *reinterpret_cast<const float4*>(r + 4);
        int nit = (cnt + 3) >> 2;
        for (int it = 0; it < nit; ++it) {
            // rows for next iteration (index already resident)
            const float* rn = emb + (size_t)i_nxt * 128 + 8 * l16;
            float4 n0 = *reinterpret_cast<const float4*>(rn);
            float4 n1 = *reinterpret_cast<const float4*>(rn + 4);
            // index for the iteration after that
            int i_n2 = ob[min(e + 8, last)];
            float part = v0.x * wa0.x + v0.y * wa0.y + v0.z * wa0.z + v0.w * wa0.w
                       + v1.x * wa1.x + v1.y * wa1.y + v1.z * wa1.z + v1.w * wa1.w;
            part += __shfl_xor(part, 1);
            part += __shfl_xor(part, 2);
            part += __shfl_xor(part, 4);
            part += __shfl_xor(part, 8);
            float ex = (e <= last) ? __expf(part) : 0.f;
            Z += ex;
            a0.x = fmaf(ex, v0.x, a0.x);
            a0.y = fmaf(ex, v0.y, a0.y);
            a0.z = fmaf(ex, v0.z, a0.z);
            a0.w = fmaf(ex, v0.w, a0.w);
            a1.x = fmaf(ex, v1.x, a1.x);
            a1.y = fmaf(ex, v1.y, a1.y);
            a1.z = fmaf(ex, v1.z, a1.z);
            a1.w = fmaf(ex, v1.w, a1.w);
            v0 = n0; v1 = n1; i_nxt = i_n2; e += 4;
        }
    }
    // combine the 4 groups (lane sets l16+16k own the same dims)
#pragma unroll
    for (int m = 16; m <= 32; m <<= 1) {
        a0.x += __shfl_xor(a0.x, m);
        a0.y += __shfl_xor(a0.y, m);
        a0.z += __shfl_xor(a0.z, m);
        a0.w += __shfl_xor(a0.w, m);
        a1.x += __shfl_xor(a1.x, m);
        a1.y += __shfl_xor(a1.y, m);
        a1.z += __shfl_xor(a1.z, m);
        a1.w += __shfl_xor(a1.w, m);
        Z    += __shfl_xor(Z,    m);
    }
    float rn_ = (Z > 0.f) ? (1.0f / Z) : 0.f;
    if (g == 0) {
        float* o = pooled + (size_t)wave * 128 + 8 * l16;
        *reinterpret_cast<float4*>(o)     = make_float4(a0.x * rn_, a0.y * rn_, a0.z * rn_, a0.w * rn_);
        *reinterpret_cast<float4*>(o + 4) = make_float4(a1.x * rn_, a1.y * rn_, a1.z * rn_, a1.w * rn_);
    }
}

// ---------------- kernel 5: projection out = pooled @ w_out^T ---------------
// In-place on d_out. Each staged-w float4 feeds 4 samples (w LDS traffic /4);
// p reads are wave-uniform LDS broadcasts (conflict-free).
#define SPB 8
__global__ __launch_bounds__(256, 4) void k_proj(
        const float* __restrict__ w_out, float* __restrict__ io, int S) {
    __shared__ float wl[128][68];           // k-half of w_out, padded rows
    __shared__ float pl[SPB][64];           // k-half of 8 pooled rows
    int t = threadIdx.x;
    int d = t & 127;
    int h = t >> 7;                         // 0 or 1
    int s0 = blockIdx.x * SPB;
    float acc[4] = {0.f, 0.f, 0.f, 0.f};    // samples s0 + 2j + h

    for (int ph = 0; ph < 2; ++ph) {
        __syncthreads();                    // prev phase's LDS reads done
        for (int j = t; j < 2048; j += 256) {
            int r = j >> 4, c4 = j & 15;
            float4 wv = reinterpret_cast<const float4*>(w_out + (size_t)r * 128 + ph * 64)[c4];
            *reinterpret_cast<float4*>(&wl[r][c4 * 4]) = wv;
        }
        if (t < 128) {
            int sm = t >> 4, c4 = t & 15;
            int ss = s0 + sm;
            float4 pv = (ss < S)
                ? reinterpret_cast<const float4*>(io + (size_t)ss * 128 + ph * 64)[c4]
                : make_float4(0.f, 0.f, 0.f, 0.f);
            *reinterpret_cast<float4*>(&pl[sm][c4 * 4]) = pv;
        }
        __syncthreads();
#pragma unroll
        for (int k4 = 0; k4 < 16; ++k4) {
            float4 wv = *reinterpret_cast<const float4*>(&wl[d][k4 * 4]);
#pragma unroll
            for (int j = 0; j < 4; ++j) {
                float4 pv = *reinterpret_cast<const float4*>(&pl[2 * j + h][k4 * 4]);
                acc[j] = fmaf(wv.x, pv.x, acc[j]);
                acc[j] = fmaf(wv.y, pv.y, acc[j]);
                acc[j] = fmaf(wv.z, pv.z, acc[j]);
                acc[j] = fmaf(wv.w, pv.w, acc[j]);
            }
        }
    }
    // every thread passed the post-stage barrier of phase 1 -> all io reads
    // in this block are complete; rows are block-exclusive -> safe overwrite
#pragma unroll
    for (int j = 0; j < 4; ++j) {
        int s = s0 + 2 * j + h;
        if (s < S) io[(size_t)s * 128 + d] = acc[j];
    }
}

extern "C" void kernel_launch(void* const* d_in, const int* in_sizes, int n_in,
                              void* d_out, int out_size, void* d_ws, size_t ws_size,
                              hipStream_t stream) {
    const float* emb   = (const float*)d_in[0];
    const float* w_att = (const float*)d_in[1];
    const float* w_out = (const float*)d_in[2];
    const int*   idx   = (const int*)d_in[3];
    const int N = in_sizes[0] / 128;
    const int S = out_size / 128;

    char* ws = (char*)d_ws;
    int* counts = (int*)(ws + 0);                  // 32 KB
    int* base   = (int*)(ws + 32 * 1024);          // 32 KB
    int* rb     = (int*)(ws + 128 * 1024);         // NB * S ints = 2 MB
    int* order  = (int*)(ws + 128 * 1024 + (size_t)NB * 8192 * 4);  // N ints
    float* out  = (float*)d_out;                   // pooled lives here briefly

    hipMemsetAsync(counts, 0, (size_t)S * sizeof(int), stream);
    k_hist2  <<<NB, 1024, 0, stream>>>(idx, counts, rb, N, S);
    k_scan   <<<1, 1024, 0, stream>>>(counts, base, S);
    k_scatter2<<<NB, 1024, 0, stream>>>(idx, base, rb, order, N, S);
    k_pool   <<<(S + 3) / 4, 256, 0, stream>>>(emb, w_att, base, counts, order, out, S);
    k_proj   <<<(S + SPB - 1) / SPB, 256, 0, stream>>>(w_out, out, S);
}